// Round 2
// baseline (115.754 us; speedup 1.0000x reference)
//
#include <hip/hip_runtime.h>
#include <hip/hip_bf16.h>

#define MARGIN  0.2f
#define NEG_INF -1e30f
#define POS_INF 1e30f

#define B_SZ 8192
#define D_SZ 128

typedef __bf16 bf16x8 __attribute__((ext_vector_type(8)));
typedef __bf16 bf16x4 __attribute__((ext_vector_type(4)));
typedef float  f32x4  __attribute__((ext_vector_type(4)));

// ---------------- Kernel 1: fp32 -> bf16 convert ----------------
__global__ __launch_bounds__(256) void k_convert(const float* __restrict__ in,
                                                 __bf16* __restrict__ out, int n) {
    int i = (blockIdx.x * 256 + threadIdx.x) * 4;
    if (i < n) {
        float4 v = *reinterpret_cast<const float4*>(in + i);
        bf16x4 o;
        o[0] = (__bf16)v.x; o[1] = (__bf16)v.y; o[2] = (__bf16)v.z; o[3] = (__bf16)v.w;
        *reinterpret_cast<bf16x4*>(out + i) = o;
    }
}

// ---------------- Kernel 2: fused GEMM + hard mining (partial) ----------------
// grid: (128 row-blocks, 8 col-splits). Block = 256 thr = 4 waves.
// Each wave owns ALL 64 rows of the row-block (A frags in registers, K=128),
// and 1/4 of the split's 1024 columns (16 tiles of 16 cols).
__global__ __launch_bounds__(256) void k_mine(const __bf16* __restrict__ imb,
                                              const int* __restrict__ ids,
                                              float* __restrict__ wsmax,
                                              float* __restrict__ wsmin) {
    const int rb  = blockIdx.x;          // 0..127
    const int cs  = blockIdx.y;          // 0..7
    const int tid = threadIdx.x;
    const int w    = tid >> 6;
    const int lane = tid & 63;
    const int quad = lane >> 4;          // 0..3
    const int lr   = lane & 15;          // 0..15

    __shared__ int   ids_s[1024];
    __shared__ float red_mx[4][64];
    __shared__ float red_mn[4][64];

    const int colsplit0 = cs * 1024;
    // stage this split's col ids
    reinterpret_cast<int4*>(ids_s)[tid] =
        reinterpret_cast<const int4*>(ids + colsplit0)[tid];

    const int rowbase = rb * 64;

    // A fragments: 4 strips x 4 K-frags. A layout (16x16x32): row = lane&15,
    // k = kf*32 + quad*8 + j  -> 16 contiguous bytes per lane.
    bf16x8 afrag[4][4];
    #pragma unroll
    for (int s = 0; s < 4; ++s) {
        const __bf16* p = imb + (size_t)(rowbase + s * 16 + lr) * D_SZ + quad * 8;
        #pragma unroll
        for (int kf = 0; kf < 4; ++kf)
            afrag[s][kf] = *reinterpret_cast<const bf16x8*>(p + kf * 32);
    }

    // per-lane row indices/ids for C layout: row = quad*4 + reg (within strip)
    int   rowv[4][4];
    int   rid [4][4];
    float mxn [4][4];
    float mnp [4][4];
    #pragma unroll
    for (int s = 0; s < 4; ++s)
        #pragma unroll
        for (int r = 0; r < 4; ++r) {
            rowv[s][r] = rowbase + s * 16 + quad * 4 + r;
            rid [s][r] = ids[rowv[s][r]];
            mxn [s][r] = NEG_INF;
            mnp [s][r] = POS_INF;
        }

    __syncthreads();

    #pragma unroll 1
    for (int t = 0; t < 16; ++t) {
        const int tile    = w * 16 + t;
        const int colbase = colsplit0 + tile * 16;
        const int colv    = colbase + lr;
        const int cid     = ids_s[tile * 16 + lr];

        bf16x8 bfrag[4];
        const __bf16* q = imb + (size_t)colv * D_SZ + quad * 8;
        #pragma unroll
        for (int kf = 0; kf < 4; ++kf)
            bfrag[kf] = *reinterpret_cast<const bf16x8*>(q + kf * 32);

        #pragma unroll
        for (int s = 0; s < 4; ++s) {
            f32x4 acc = {0.f, 0.f, 0.f, 0.f};
            #pragma unroll
            for (int kf = 0; kf < 4; ++kf)
                acc = __builtin_amdgcn_mfma_f32_16x16x32_bf16(afrag[s][kf], bfrag[kf], acc, 0, 0, 0);
            #pragma unroll
            for (int r = 0; r < 4; ++r) {
                float sv   = acc[r];
                bool  same = (rid[s][r] == cid);
                bool  diag = (rowv[s][r] == colv);
                mxn[s][r] = fmaxf(mxn[s][r], same ? NEG_INF : sv);
                mnp[s][r] = fminf(mnp[s][r], (same && !diag) ? sv : POS_INF);
            }
        }
    }

    // reduce across the 16 lanes (same quad) that share each row
    #pragma unroll
    for (int s = 0; s < 4; ++s)
        #pragma unroll
        for (int r = 0; r < 4; ++r) {
            float mx = mxn[s][r];
            float mn = mnp[s][r];
            #pragma unroll
            for (int m = 1; m < 16; m <<= 1) {
                mx = fmaxf(mx, __shfl_xor(mx, m, 64));
                mn = fminf(mn, __shfl_xor(mn, m, 64));
            }
            if (lr == 0) {
                int rl = s * 16 + quad * 4 + r;
                red_mx[w][rl] = mx;
                red_mn[w][rl] = mn;
            }
        }
    __syncthreads();

    if (tid < 64) {
        float mx = red_mx[0][tid];
        float mn = red_mn[0][tid];
        #pragma unroll
        for (int ww = 1; ww < 4; ++ww) {
            mx = fmaxf(mx, red_mx[ww][tid]);
            mn = fminf(mn, red_mn[ww][tid]);
        }
        wsmax[cs * B_SZ + rowbase + tid] = mx;
        wsmin[cs * B_SZ + rowbase + tid] = mn;
    }
}

// ---------------- Kernel 3: final reduce ----------------
__global__ __launch_bounds__(256) void k_final(const float* __restrict__ wsmax,
                                               const float* __restrict__ wsmin,
                                               float* __restrict__ out) {
    int r = blockIdx.x * 256 + threadIdx.x;
    float mx = NEG_INF;
    float mn = 0.0f;   // zeroed diagonal is always a positive candidate
    #pragma unroll
    for (int cs = 0; cs < 8; ++cs) {
        mx = fmaxf(mx, wsmax[cs * B_SZ + r]);
        mn = fminf(mn, wsmin[cs * B_SZ + r]);
    }
    float cost = fmaxf(MARGIN + mx - mn, 0.0f);
    #pragma unroll
    for (int m = 1; m < 64; m <<= 1)
        cost += __shfl_xor(cost, m, 64);
    __shared__ float part[4];
    int lane = threadIdx.x & 63, w = threadIdx.x >> 6;
    if (lane == 0) part[w] = cost;
    __syncthreads();
    if (threadIdx.x == 0)
        atomicAdd(out, part[0] + part[1] + part[2] + part[3]);
}

extern "C" void kernel_launch(void* const* d_in, const int* in_sizes, int n_in,
                              void* d_out, int out_size, void* d_ws, size_t ws_size,
                              hipStream_t stream) {
    const float* im  = (const float*)d_in[0];
    const int*   ids = (const int*)d_in[1];
    float*       out = (float*)d_out;

    __bf16* imb   = (__bf16*)d_ws;                                   // 2 MB
    float*  wsmax = (float*)((char*)d_ws + (size_t)B_SZ * D_SZ * 2); // 8*8192 f32
    float*  wsmin = wsmax + 8 * B_SZ;

    hipMemsetAsync(d_out, 0, sizeof(float), stream);

    k_convert<<<(B_SZ * D_SZ) / (256 * 4), 256, 0, stream>>>(im, imb, B_SZ * D_SZ);
    k_mine<<<dim3(128, 8), 256, 0, stream>>>(imb, ids, wsmax, wsmin);
    k_final<<<B_SZ / 256, 256, 0, stream>>>(wsmax, wsmin, out);
}